// Round 3
// baseline (201.505 us; speedup 1.0000x reference)
//
#include <hip/hip_runtime.h>
#include <stdint.h>

#define B_ 8
#define H_ 128
#define W_ 128
#define D_ 128
#define N_ (H_*W_)
#define M_ (B_*N_)   // 131072 rows total

typedef __attribute__((ext_vector_type(8))) short short8;
typedef __attribute__((ext_vector_type(4))) float floatx4;

typedef const __attribute__((address_space(1))) void* gas_t;
typedef __attribute__((address_space(3))) void* las_t;

__device__ inline unsigned short f2bf(float f){
  union { float f; unsigned int i; } c; c.f = f;
  unsigned int x = c.i;
  x += 0x7FFF + ((x >> 16) & 1);   // RNE
  return (unsigned short)(x >> 16);
}
__device__ inline float bflo(unsigned int u){
  union { unsigned int i; float f; } c; c.i = u << 16; return c.f;
}
__device__ inline float bfhi(unsigned int u){
  union { unsigned int i; float f; } c; c.i = u & 0xFFFF0000u; return c.f;
}

// ---------------- kernel 0: W -> W^T bf16 ----------------
__global__ void wtrans_kernel(const float* __restrict__ Wq, const float* __restrict__ Wk,
                              const float* __restrict__ Wv, unsigned short* __restrict__ Wt){
  const float* src = blockIdx.x == 0 ? Wq : (blockIdx.x == 1 ? Wk : Wv);
  unsigned short* dst = Wt + blockIdx.x * (D_*D_);
  const int i = blockIdx.y * 256 + threadIdx.x;
  const int k = i >> 7, n = i & 127;
  dst[n*D_ + k] = f2bf(src[i]);
}

// ---------------- kernel 1: FUSED QKV projection ----------------
// 64-row tiles (grid 2048), LDS 48 KB -> 3 blocks/CU (was 2), 6 barriers/block
// (was 19). Swapped-operand MFMA (mfma(b,a) computes C^T mapping): each lane
// holds 4 CONSECUTIVE output cols -> direct uint2 global store, no LDS
// round-trip epilogue. B(which+1) global_load_lds issued before the epilogue
// stores so its latency hides under them; B0 issued before the A-stage.
__global__ __launch_bounds__(256, 3) void qkv_gemm_kernel(
    const float* __restrict__ x, const unsigned short* __restrict__ Wt,
    const float* __restrict__ bq, const float* __restrict__ bk, const float* __restrict__ bv,
    unsigned short* __restrict__ Q, unsigned short* __restrict__ K, unsigned short* __restrict__ V)
{
  const int rowTile = blockIdx.x;

  __shared__ unsigned short lds[24576];  // A [0,8192) + B [8192,24576) ushorts = 48 KB

  const int t = threadIdx.x;
  const int wave = t >> 6, lane = t & 63;

  // ---- issue B0 stage first (async, no regs) so it flies under the A-stage
  {
    const unsigned short* W0 = Wt;  // which=0
    #pragma unroll
    for (int p = 0; p < 8; ++p){
      int s = p*256 + t;                 // 16B chunk id
      int n = s >> 4, cp = s & 15, c = cp ^ (n & 7);
      const unsigned short* gp = W0 + n*128 + c*8;
      unsigned short* lp = (unsigned short*)lds + 8192 + p*2048 + wave*512;
      __builtin_amdgcn_global_load_lds((gas_t)(const void*)gp, (las_t)(void*)lp, 16, 0, 0);
    }
  }

  // ---- A stage: 64 rows of x, fp32 -> bf16, swizzled ds_write_b128
  {
    const float* xrow = x + (size_t)rowTile * 64 * D_;
    #pragma unroll
    for (int p = 0; p < 4; ++p){
      int s = p*256 + t;
      int r = s >> 4, cp = s & 15, c = cp ^ (r & 7);
      const float* gp = xrow + r*D_ + c*8;
      float4 f0 = *(const float4*)gp;
      float4 f1 = *(const float4*)(gp + 4);
      uint4 pk;
      pk.x = (unsigned)f2bf(f0.x) | ((unsigned)f2bf(f0.y) << 16);
      pk.y = (unsigned)f2bf(f0.z) | ((unsigned)f2bf(f0.w) << 16);
      pk.z = (unsigned)f2bf(f1.x) | ((unsigned)f2bf(f1.y) << 16);
      pk.w = (unsigned)f2bf(f1.z) | ((unsigned)f2bf(f1.w) << 16);
      *(uint4*)&lds[s*8] = pk;
    }
  }
  __syncthreads();   // A written, B0 landed (barrier drains vmcnt)

  const int wm = (wave >> 1) * 32, wn = (wave & 1) * 64;  // wave -> 32x64 quadrant
  const int m0 = lane & 15, quad = lane >> 4;

  #pragma unroll
  for (int which = 0; which < 3; ++which){
    // ---- MFMA: acc[j][i] = mfma(b[j], a[i]) -> lane holds C[row=wm+i*16+m0]
    //      [col = wn+j*16+quad*4 + r], r=0..3 (consecutive cols!)
    floatx4 acc[4][2] = {};
    #pragma unroll
    for (int kk = 0; kk < 4; ++kk){
      short8 a[2], b[4];
      #pragma unroll
      for (int i = 0; i < 2; ++i){
        int row = wm + i*16 + m0;
        int c = (kk*4 + quad) ^ (row & 7);
        a[i] = *(const short8*)&lds[row*128 + c*8];
      }
      #pragma unroll
      for (int j = 0; j < 4; ++j){
        int n = wn + j*16 + m0;
        int c = (kk*4 + quad) ^ (n & 7);
        b[j] = *(const short8*)&lds[8192 + n*128 + c*8];
      }
      #pragma unroll
      for (int j = 0; j < 4; ++j)
        #pragma unroll
        for (int i = 0; i < 2; ++i)
          acc[j][i] = __builtin_amdgcn_mfma_f32_16x16x32_bf16(b[j], a[i], acc[j][i], 0, 0, 0);
    }
    __syncthreads();   // all waves done reading B[which] -> safe to overwrite

    // ---- issue B[which+1] now; latency hides under the epilogue stores
    if (which < 2){
      const unsigned short* Wnext = Wt + (which + 1) * (D_*D_);
      #pragma unroll
      for (int p = 0; p < 8; ++p){
        int s = p*256 + t;
        int n = s >> 4, cp = s & 15, c = cp ^ (n & 7);
        const unsigned short* gp = Wnext + n*128 + c*8;
        unsigned short* lp = (unsigned short*)lds + 8192 + p*2048 + wave*512;
        __builtin_amdgcn_global_load_lds((gas_t)(const void*)gp, (las_t)(void*)lp, 16, 0, 0);
      }
    }

    // ---- epilogue: direct global stores (no LDS), 8B/lane per (i,j)
    {
      const float* bias = which == 0 ? bq : (which == 1 ? bk : bv);
      unsigned short* Out = which == 0 ? Q : (which == 1 ? K : V);
      unsigned short* Outp = Out + (size_t)rowTile * 64 * D_;
      #pragma unroll
      for (int j = 0; j < 4; ++j){
        const float4 bb = *(const float4*)&bias[wn + j*16 + quad*4];
        #pragma unroll
        for (int i = 0; i < 2; ++i){
          const int row = wm + i*16 + m0;
          uint2 pk;
          pk.x = (unsigned)f2bf(acc[j][i][0] + bb.x) | ((unsigned)f2bf(acc[j][i][1] + bb.y) << 16);
          pk.y = (unsigned)f2bf(acc[j][i][2] + bb.z) | ((unsigned)f2bf(acc[j][i][3] + bb.w) << 16);
          *(uint2*)(Outp + row*D_ + wn + j*16 + quad*4) = pk;
        }
      }
    }

    if (which < 2) __syncthreads();  // B[which+1] landed (vmcnt drained at barrier)
  }
}

// ---------------- kernel 2: 3x3 window attention ----------------
// (unchanged from round 2 — spill-free batched loads, ~50 us)
__global__ __launch_bounds__(256, 2) void attn_kernel(
    const unsigned short* __restrict__ Q, const unsigned short* __restrict__ K,
    const unsigned short* __restrict__ V, float* __restrict__ out)
{
  const int t = threadIdx.x;
  const int e8 = t & 7;                      // which 16-dim chunk
  const int pix = blockIdx.x * 32 + (t >> 3);
  const int w = pix & 127;
  const int h = (pix >> 7) & 127;
  const int bbase = pix & ~(N_ - 1);         // first pixel of this batch image
  const float scale = 0.08838834764831845f;  // 1/sqrt(128)
  const int doff = e8 * 16;
  const size_t off = (size_t)pix * D_ + doff;

  // ---- neighbor pixel indices, clamped into the image (always valid)
  int npix[9]; bool okm[9];
  #pragma unroll
  for (int i = 0; i < 9; ++i){
    const int dy = i/3 - 1, dx = i%3 - 1;
    const int hh = h + dy, ww = w + dx;
    okm[i] = ((unsigned)hh < 128u) && ((unsigned)ww < 128u);
    const int hc = min(max(hh, 0), 127);
    const int wc = min(max(ww, 0), 127);
    npix[i] = bbase + hc*W_ + wc;
  }

  // ---- issue q, then ALL 9 K, then ALL 9 V (unconditional -> batchable)
  uint4 qu0, qu1;
  {
    const unsigned short* qp = Q + off;
    qu0 = *(const uint4*)qp;
    qu1 = *(const uint4*)(qp + 8);
  }
  uint4 ku[9][2];
  #pragma unroll
  for (int i = 0; i < 9; ++i){
    const unsigned short* kp = K + (size_t)npix[i]*D_ + doff;
    ku[i][0] = *(const uint4*)kp;
    ku[i][1] = *(const uint4*)(kp + 8);
  }
  uint4 vu[9][2];
  #pragma unroll
  for (int i = 0; i < 9; ++i){
    const unsigned short* vp = V + (size_t)npix[i]*D_ + doff;
    vu[i][0] = *(const uint4*)vp;
    vu[i][1] = *(const uint4*)(vp + 8);
  }

  // ---- q unpack + scale
  float q[16];
  {
    unsigned uu[8] = {qu0.x, qu0.y, qu0.z, qu0.w, qu1.x, qu1.y, qu1.z, qu1.w};
    #pragma unroll
    for (int e = 0; e < 8; ++e){
      q[e*2]     = bflo(uu[e]) * scale;
      q[e*2 + 1] = bfhi(uu[e]) * scale;
    }
  }

  // ---- partial dot products (16 dims); OOB -> exact 0 via scalar select
  float s[9];
  #pragma unroll
  for (int i = 0; i < 9; ++i){
    unsigned uu[8] = {ku[i][0].x, ku[i][0].y, ku[i][0].z, ku[i][0].w,
                      ku[i][1].x, ku[i][1].y, ku[i][1].z, ku[i][1].w};
    float acc = 0.f;
    #pragma unroll
    for (int e = 0; e < 8; ++e){
      acc += q[e*2]     * bflo(uu[e]);
      acc += q[e*2 + 1] * bfhi(uu[e]);
    }
    s[i] = okm[i] ? acc : 0.f;
  }
  // 8-lane reduce (all 8 lanes of a pixel share okm, so select-then-reduce ok)
  #pragma unroll
  for (int i = 0; i < 9; ++i){
    s[i] += __shfl_xor(s[i], 1, 64);
    s[i] += __shfl_xor(s[i], 2, 64);
    s[i] += __shfl_xor(s[i], 4, 64);
  }

  // ---- softmax (OOB score is exactly 0, participates — ref zero-pad semantics)
  float m = s[0];
  #pragma unroll
  for (int i = 1; i < 9; ++i) m = fmaxf(m, s[i]);
  float p[9]; float l = 0.f;
  #pragma unroll
  for (int i = 0; i < 9; ++i){ p[i] = __expf(s[i] - m); l += p[i]; }
  const float inv = 1.f / l;

  // ---- PV accumulate; OOB contributes 0 via select on pi
  float o[16];
  #pragma unroll
  for (int d = 0; d < 16; ++d) o[d] = 0.f;
  #pragma unroll
  for (int i = 0; i < 9; ++i){
    const float pi = okm[i] ? p[i] * inv : 0.f;
    unsigned uu[8] = {vu[i][0].x, vu[i][0].y, vu[i][0].z, vu[i][0].w,
                      vu[i][1].x, vu[i][1].y, vu[i][1].z, vu[i][1].w};
    #pragma unroll
    for (int e = 0; e < 8; ++e){
      o[e*2]     += pi * bflo(uu[e]);
      o[e*2 + 1] += pi * bfhi(uu[e]);
    }
  }

  float* op = out + off;
  #pragma unroll
  for (int c = 0; c < 4; ++c){
    float4 v4 = make_float4(o[c*4], o[c*4+1], o[c*4+2], o[c*4+3]);
    *(float4*)(op + c*4) = v4;
  }
}

extern "C" void kernel_launch(void* const* d_in, const int* in_sizes, int n_in,
                              void* d_out, int out_size, void* d_ws, size_t ws_size,
                              hipStream_t stream)
{
  const float* x  = (const float*)d_in[0];
  const float* Wq = (const float*)d_in[1];
  const float* bq = (const float*)d_in[2];
  const float* Wk = (const float*)d_in[3];
  const float* bk = (const float*)d_in[4];
  const float* Wv = (const float*)d_in[5];
  const float* bv = (const float*)d_in[6];
  float* out = (float*)d_out;

  char* ws = (char*)d_ws;
  unsigned short* Wt = (unsigned short*)ws;                                   // 96 KB
  unsigned short* Q  = (unsigned short*)(ws + (1<<17));
  unsigned short* K  = (unsigned short*)(ws + (1<<17) + (size_t)M_*D_*2);
  unsigned short* V  = (unsigned short*)(ws + (1<<17) + (size_t)2*M_*D_*2);   // ~96.1 MB

  hipLaunchKernelGGL(wtrans_kernel, dim3(3, 64), dim3(256), 0, stream, Wq, Wk, Wv, Wt);
  hipLaunchKernelGGL(qkv_gemm_kernel, dim3(M_/64), dim3(256), 0, stream,
                     x, Wt, bq, bk, bv, Q, K, V);
  hipLaunchKernelGGL(attn_kernel, dim3(M_/32), dim3(256), 0, stream, Q, K, V, out);
}